// Round 5
// baseline (254.678 us; speedup 1.0000x reference)
//
#include <hip/hip_runtime.h>
#include <math.h>

// Problem constants (fixed by reference: B=32,T=1024,D=256,K=1024)
#define N_ROWS 32768
#define DIM    256
#define KCODES 1024
// Screen is single-pass bf16 (s~ = e2 - 2*xh.eh). Score error: sigma ~2.8e-5,
// max over 3.4e7 samples ~1.5e-4; plus numpy fp32 rounding band ~6e-5.
// DELTA = 5e-4 covers flips at >10 sigma; ambiguous rows get exact fp32
// rescore (R2-proven numpy-rounding path).
#define DELTA  5.0e-4f

typedef float f32x4 __attribute__((ext_vector_type(4)));
typedef short s16x8 __attribute__((ext_vector_type(8)));

__device__ inline unsigned short bf_rne(float f) {
    unsigned u = __float_as_uint(f);
    return (unsigned short)((u + 0x7FFFu + ((u >> 16) & 1u)) >> 16);
}

// lex insert (v,ix) into ascending top-4 (ties -> lower index first)
__device__ inline void ins4(float v, int ix, float (&tv)[4], int (&ti)[4]) {
    if (v < tv[3] || (v == tv[3] && ix < ti[3])) {
        if (v < tv[2] || (v == tv[2] && ix < ti[2])) {
            tv[3] = tv[2]; ti[3] = ti[2];
            if (v < tv[1] || (v == tv[1] && ix < ti[1])) {
                tv[2] = tv[1]; ti[2] = ti[1];
                if (v < tv[0] || (v == tv[0] && ix < ti[0])) {
                    tv[1] = tv[0]; ti[1] = ti[0]; tv[0] = v; ti[0] = ix;
                } else { tv[1] = v; ti[1] = ix; }
            } else { tv[2] = v; ti[2] = ix; }
        } else { tv[3] = v; ti[3] = ix; }
    }
}

// async global->LDS, 16B per lane. LDS dest = wave-uniform base + lane*16 (HW rule).
__device__ __forceinline__ void gl_lds16(const void* gp, void* lp) {
    __builtin_amdgcn_global_load_lds(
        (__attribute__((address_space(1))) void*)(void*)gp,
        (__attribute__((address_space(3))) void*)lp, 16, 0, 0);
}

// ---------------------------------------------------------------------------
// E prep only (e2 pairwise + bf16 hi of E) — verbatim R2-proven body.
// X's sum-of-squares no longer has its own pass: decide's rescue path (~7% of
// rows) recomputes it serially in the exact same numpy-pairwise order.
__global__ __launch_bounds__(256) void prep_kernel(const float* __restrict__ E,
                                                   float* __restrict__ e2,
                                                   unsigned short* __restrict__ Eh) {
    __shared__ float sq[4][260];
    const int wave = threadIdx.x >> 6;
    const int lane = threadIdx.x & 63;
    const int row = blockIdx.x * 4 + wave;
    const float4* rp = (const float4*)(E + (size_t)row * DIM);
    float4 v = rp[lane];
    sq[wave][lane * 4 + 0] = v.x * v.x;
    sq[wave][lane * 4 + 1] = v.y * v.y;
    sq[wave][lane * 4 + 2] = v.z * v.z;
    sq[wave][lane * 4 + 3] = v.w * v.w;
    float fs[4] = {v.x, v.y, v.z, v.w};
    ushort4 hv;
    unsigned short* hp = (unsigned short*)&hv;
#pragma unroll
    for (int j = 0; j < 4; ++j) hp[j] = bf_rne(fs[j]);
    *(ushort4*)(Eh + (size_t)row * DIM + lane * 4) = hv;
    if (lane < 8) {
#pragma clang fp contract(off)
        const int j = lane;
        float rA = sq[wave][j];
#pragma unroll
        for (int m = 1; m < 16; ++m) rA += sq[wave][8 * m + j];
        float rB = sq[wave][128 + j];
#pragma unroll
        for (int m = 1; m < 16; ++m) rB += sq[wave][128 + 8 * m + j];
        rA = rA + __shfl_xor(rA, 1, 64); rA = rA + __shfl_xor(rA, 2, 64);
        rA = rA + __shfl_xor(rA, 4, 64);
        rB = rB + __shfl_xor(rB, 1, 64); rB = rB + __shfl_xor(rB, 2, 64);
        rB = rB + __shfl_xor(rB, 4, 64);
        if (j == 0) e2[row] = rA + rB;
    }
}

// Exact serial replica of the wave-parallel numpy-pairwise row sum-of-squares:
// sq[i]=x[i]*x[i] (rounded mult), per-j 16-term serial sums, then the shfl-tree
// association ((j0+j1)+(j2+j3))+((j4+j5)+(j6+j7)), halves added last (rA+rB).
__device__ float x2_exact(const float* __restrict__ xr) {
#pragma clang fp contract(off)
    float rr[16];
#pragma unroll
    for (int j = 0; j < 8; ++j) {
        float a = xr[j] * xr[j];
#pragma unroll
        for (int m = 1; m < 16; ++m) { float t = xr[8 * m + j]; float s = t * t; a += s; }
        rr[j] = a;
        float b = xr[128 + j] * xr[128 + j];
#pragma unroll
        for (int m = 1; m < 16; ++m) { float t = xr[128 + 8 * m + j]; float s = t * t; b += s; }
        rr[8 + j] = b;
    }
    float a01 = rr[0] + rr[1], a23 = rr[2] + rr[3];
    float a45 = rr[4] + rr[5], a67 = rr[6] + rr[7];
    float A = (a01 + a23) + (a45 + a67);
    float b01 = rr[8] + rr[9], b23 = rr[10] + rr[11];
    float b45 = rr[12] + rr[13], b67 = rr[14] + rr[15];
    float Bt = (b01 + b23) + (b45 + b67);
    return A + Bt;
}

// ---------------------------------------------------------------------------
// Fused screen + decide + gather. 512 threads = 8 waves, 64 rows/block,
// grid 512 -> 2 blocks/CU (LDS ~68 KB), 4 waves/SIMD.
// __launch_bounds__(512, 2) -> 128-VGPR budget; kernel needs ~110 (xh 64 frag
// VGPRs + acc + top4 + temps) -> no spill (R4: WRITE_SIZE clean at 65.7 MB).
// Inner loop is branchless (R4's wave-uniform __any guard serialized the
// select chains and cost 60% -> reverted; R4 post-mortem).
// Wave w: row-pair p=w&1 (rows p*32..p*32+31, 2 tiles of 16), code quarter
// grp=w>>1. Staging: async global_load_lds, double-buffered, one barrier per
// chunk (proven R1-R3 pattern).
__global__ __launch_bounds__(512, 2) void vq_fused_kernel(const float* __restrict__ X,
                                                          const unsigned short* __restrict__ Eh,
                                                          const float* __restrict__ e2g,
                                                          const float* __restrict__ E,
                                                          float* __restrict__ out0,
                                                          float* __restrict__ out1,
                                                          float* __restrict__ out2) {
    __shared__ __align__(16) short bh_lds[2][16384];  // 2 x 32 KB code chunks
    __shared__ float e2_lds[KCODES];                  // 4 KB
    __shared__ int sidx[64];

    const int tid  = threadIdx.x;
    const int w    = tid >> 6;
    const int l    = tid & 63;
    const int c16  = l & 15;
    const int quad = l >> 4;
    const int p    = w & 1;    // row-pair (rows p*32 .. p*32+31)
    const int grp  = w >> 1;   // code quarter: nt = grp
    const int row0 = blockIdx.x * 64;

    // e2 -> LDS once (drained by first barrier)
    if (tid < 256) *(float4*)&e2_lds[tid * 4] = *(const float4*)&e2g[tid * 4];

    // ---- X fragments (B-operand): 2 tiles x 16 rows, hi only, K=256 ----
    s16x8 xh[2][8];
#pragma unroll
    for (int t = 0; t < 2; ++t) {
        const float* xrow = X + (size_t)(row0 + p * 32 + t * 16 + c16) * DIM + quad * 8;
#pragma unroll
        for (int ks = 0; ks < 8; ++ks) {
            float4 f0 = *(const float4*)(xrow + ks * 32);
            float4 f1 = *(const float4*)(xrow + ks * 32 + 4);
            float fs[8] = {f0.x, f0.y, f0.z, f0.w, f1.x, f1.y, f1.z, f1.w};
#pragma unroll
            for (int j = 0; j < 8; ++j) xh[t][ks][j] = (short)bf_rne(fs[j]);
        }
    }

    float tva[4], tvb[4];
    int   tia[4], tib[4];
#pragma unroll
    for (int s = 0; s < 4; ++s) {
        tva[s] = INFINITY; tvb[s] = INFINITY;
        tia[s] = 0x7fffffff; tib[s] = 0x7fffffff;
    }

    // stage codes [cb, cb+64): 32 granules of 1KB; 8 waves x 4 each
    auto stage = [&](int bsel, int cb) {
        const unsigned short* Ehc = Eh + (size_t)cb * DIM;
#pragma unroll
        for (int gg = 0; gg < 4; ++gg) {
            const int g  = w + gg * 8;              // wave-uniform, 0..31
            const int nt = g >> 3, ks = g & 7;
            const size_t eo = (size_t)(nt * 16 + c16) * DIM + ks * 32 + quad * 8;
            gl_lds16(Ehc + eo, &bh_lds[bsel][g * 512]);
        }
    };

    stage(0, 0);

    for (int c = 0; c < 16; ++c) {
        __syncthreads();                 // buf[c&1] staged; prev chunk's reads done
        if (c < 15) stage((c + 1) & 1, (c + 1) * 64);   // prefetch under MFMAs
        const int bsel = c & 1;
        const int nt   = grp;
        f32x4 c0a = {0.f, 0.f, 0.f, 0.f};
        f32x4 c0b = c0a;
#pragma unroll
        for (int ks = 0; ks < 8; ++ks) {
            s16x8 ch = *(const s16x8*)&bh_lds[bsel][((nt * 8 + ks) * 64 + l) * 8];
            c0a = __builtin_amdgcn_mfma_f32_16x16x32_bf16(ch, xh[0][ks], c0a, 0, 0, 0);
            c0b = __builtin_amdgcn_mfma_f32_16x16x32_bf16(ch, xh[1][ks], c0b, 0, 0, 0);
        }
        f32x4 e2v = *(const f32x4*)&e2_lds[c * 64 + nt * 16 + quad * 4];
#pragma unroll
        for (int r = 0; r < 4; ++r) {
            const int code = c * 64 + nt * 16 + quad * 4 + r;
            ins4(fmaf(-2.0f, c0a[r], e2v[r]), code, tva, tia);
            ins4(fmaf(-2.0f, c0b[r], e2v[r]), code, tvb, tib);
        }
    }

    // merge top-4 across the 4 quads holding the same x-row (lanes l^16, l^32)
#pragma unroll
    for (int st = 16; st <= 32; st <<= 1) {
        float ov[4]; int oi[4];
#pragma unroll
        for (int s = 0; s < 4; ++s) {
            ov[s] = __shfl_xor(tva[s], st, 64);
            oi[s] = __shfl_xor(tia[s], st, 64);
        }
#pragma unroll
        for (int s = 0; s < 4; ++s) ins4(ov[s], oi[s], tva, tia);
#pragma unroll
        for (int s = 0; s < 4; ++s) {
            ov[s] = __shfl_xor(tvb[s], st, 64);
            oi[s] = __shfl_xor(tib[s], st, 64);
        }
#pragma unroll
        for (int s = 0; s < 4; ++s) ins4(ov[s], oi[s], tvb, tib);
    }

    // merge the 4 code-quarters (exact, order-independent lex top-4) via LDS
    // scratch carved from bh_lds[0] (dead: chunk 15 reads buf1; buf0 last
    // written by chunk-13's prefetch, last read in chunk 14).
    float* mv = (float*)&bh_lds[0][0];        // 192 slots x 4 floats (3 KB)
    int*   mi = (int*)&bh_lds[0][8192];       // 192 slots x 4 ints   (3 KB)
    if (grp >= 1 && quad == 0) {
        const int sa = (grp - 1) * 64 + p * 32 + c16;   // tile 0 slot
        const int sb = sa + 16;                          // tile 1 slot
#pragma unroll
        for (int s = 0; s < 4; ++s) {
            mv[sa * 4 + s] = tva[s]; mi[sa * 4 + s] = tia[s];
            mv[sb * 4 + s] = tvb[s]; mi[sb * 4 + s] = tib[s];
        }
    }
    __syncthreads();
    if (grp == 0 && quad == 0) {
#pragma unroll
        for (int g2 = 1; g2 < 4; ++g2) {
            const int sa = (g2 - 1) * 64 + p * 32 + c16;
            const int sb = sa + 16;
#pragma unroll
            for (int s = 0; s < 4; ++s) ins4(mv[sa * 4 + s], mi[sa * 4 + s], tva, tia);
#pragma unroll
            for (int s = 0; s < 4; ++s) ins4(mv[sb * 4 + s], mi[sb * 4 + s], tvb, tib);
        }
        // ---- decide both rows (verbatim R2-proven logic; x2 recomputed
        //      exactly in the rescue path only) ----
#pragma unroll
        for (int t = 0; t < 2; ++t) {
            float* tv = t ? tvb : tva;
            int*   ti = t ? tib : tia;
            const int r = row0 + p * 32 + t * 16 + c16;
            int best = ti[0];
            if (!(tv[1] > tv[0] + DELTA)) {
                const float* xr = X + (size_t)r * DIM;
                const float x2v = x2_exact(xr);
                float bq = INFINITY; int bi = 0x7fffffff;
                for (int cnd = 0; cnd < 4; ++cnd) {
                    if (tv[cnd] <= tv[0] + DELTA) {
                        const int k = ti[cnd];
                        const float* er = E + (size_t)k * DIM;
                        float dot = 0.f;
                        for (int d = 0; d < DIM; d += 4) {   // sequential fp32 chain
                            float4 xv = *(const float4*)(xr + d);
                            float4 ev = *(const float4*)(er + d);
                            dot = fmaf(xv.x, ev.x, dot);
                            dot = fmaf(xv.y, ev.y, dot);
                            dot = fmaf(xv.z, ev.z, dot);
                            dot = fmaf(xv.w, ev.w, dot);
                        }
                        float t1 = e2_lds[k] - 2.0f * dot;   // numpy elementwise rounding
                        float q  = t1 + x2v;
                        if (q < bq || (q == bq && k < bi)) { bq = q; bi = k; }
                    }
                }
                best = bi;
            }
            sidx[p * 32 + t * 16 + c16] = best;
            out2[r] = (float)best;
        }
    }
    __syncthreads();

    // ---- gather epilogue: 64 rows, coalesced float4 writes ----
#pragma unroll
    for (int it = 0; it < 8; ++it) {
        int f = tid + it * 512;
        int rr = f >> 6;
        int pp = f & 63;
        int ix = sidx[rr];
        float4 v = *(const float4*)(E + (size_t)ix * DIM + pp * 4);
        size_t o = (size_t)(row0 + rr) * DIM + (size_t)pp * 4;
        *(float4*)(out0 + o) = v;
        *(float4*)(out1 + o) = v;
    }
}

// ---------------------------------------------------------------------------
extern "C" void kernel_launch(void* const* d_in, const int* in_sizes, int n_in,
                              void* d_out, int out_size, void* d_ws, size_t ws_size,
                              hipStream_t stream) {
    const float* X = (const float*)d_in[0];
    const float* E = (const float*)d_in[1];

    // ws layout (all 16B-aligned): ~0.53 MB total
    float* e2 = (float*)d_ws;                              // 1024 f
    unsigned short* Eh = (unsigned short*)(e2 + KCODES);   // 262144 us

    float* out0 = (float*)d_out;
    float* out1 = out0 + (size_t)N_ROWS * DIM;
    float* out2 = out1 + (size_t)N_ROWS * DIM;

    prep_kernel<<<dim3(KCODES / 4), dim3(256), 0, stream>>>(E, e2, Eh);
    vq_fused_kernel<<<dim3(N_ROWS / 64), dim3(512), 0, stream>>>(X, Eh, e2, E,
                                                                 out0, out1, out2);
}

// Round 6
// 244.856 us; speedup vs baseline: 1.0401x; 1.0401x over previous
//
#include <hip/hip_runtime.h>
#include <math.h>

// Problem constants (fixed by reference: B=32,T=1024,D=256,K=1024)
#define N_ROWS 32768
#define DIM    256
#define KCODES 1024
// Screen is single-pass bf16 (s~ = e2 - 2*xh.eh). Score error: sigma ~2.8e-5,
// max over 3.4e7 samples ~1.5e-4; plus numpy fp32 rounding band ~6e-5.
// DELTA = 5e-4 covers flips at >10 sigma; ambiguous rows get exact fp32
// rescore (R2-proven numpy-rounding path).
#define DELTA  5.0e-4f

typedef float f32x4 __attribute__((ext_vector_type(4)));
typedef short s16x8 __attribute__((ext_vector_type(8)));

__device__ inline unsigned short bf_rne(float f) {
    unsigned u = __float_as_uint(f);
    return (unsigned short)((u + 0x7FFFu + ((u >> 16) & 1u)) >> 16);
}

// lex insert (v,ix) into ascending top-4 (ties -> lower index first)
__device__ inline void ins4(float v, int ix, float (&tv)[4], int (&ti)[4]) {
    if (v < tv[3] || (v == tv[3] && ix < ti[3])) {
        if (v < tv[2] || (v == tv[2] && ix < ti[2])) {
            tv[3] = tv[2]; ti[3] = ti[2];
            if (v < tv[1] || (v == tv[1] && ix < ti[1])) {
                tv[2] = tv[1]; ti[2] = ti[1];
                if (v < tv[0] || (v == tv[0] && ix < ti[0])) {
                    tv[1] = tv[0]; ti[1] = ti[0]; tv[0] = v; ti[0] = ix;
                } else { tv[1] = v; ti[1] = ix; }
            } else { tv[2] = v; ti[2] = ix; }
        } else { tv[3] = v; ti[3] = ix; }
    }
}

// ---------------------------------------------------------------------------
// E prep only (e2 pairwise + bf16 hi of E) — verbatim R2-proven body.
__global__ __launch_bounds__(256) void prep_kernel(const float* __restrict__ E,
                                                   float* __restrict__ e2,
                                                   unsigned short* __restrict__ Eh) {
    __shared__ float sq[4][260];
    const int wave = threadIdx.x >> 6;
    const int lane = threadIdx.x & 63;
    const int row = blockIdx.x * 4 + wave;
    const float4* rp = (const float4*)(E + (size_t)row * DIM);
    float4 v = rp[lane];
    sq[wave][lane * 4 + 0] = v.x * v.x;
    sq[wave][lane * 4 + 1] = v.y * v.y;
    sq[wave][lane * 4 + 2] = v.z * v.z;
    sq[wave][lane * 4 + 3] = v.w * v.w;
    float fs[4] = {v.x, v.y, v.z, v.w};
    ushort4 hv;
    unsigned short* hp = (unsigned short*)&hv;
#pragma unroll
    for (int j = 0; j < 4; ++j) hp[j] = bf_rne(fs[j]);
    *(ushort4*)(Eh + (size_t)row * DIM + lane * 4) = hv;
    if (lane < 8) {
#pragma clang fp contract(off)
        const int j = lane;
        float rA = sq[wave][j];
#pragma unroll
        for (int m = 1; m < 16; ++m) rA += sq[wave][8 * m + j];
        float rB = sq[wave][128 + j];
#pragma unroll
        for (int m = 1; m < 16; ++m) rB += sq[wave][128 + 8 * m + j];
        rA = rA + __shfl_xor(rA, 1, 64); rA = rA + __shfl_xor(rA, 2, 64);
        rA = rA + __shfl_xor(rA, 4, 64);
        rB = rB + __shfl_xor(rB, 1, 64); rB = rB + __shfl_xor(rB, 2, 64);
        rB = rB + __shfl_xor(rB, 4, 64);
        if (j == 0) e2[row] = rA + rB;
    }
}

// Exact serial replica of the wave-parallel numpy-pairwise row sum-of-squares:
// sq[i]=x[i]*x[i] (rounded mult), per-j 16-term serial sums, then the shfl-tree
// association ((j0+j1)+(j2+j3))+((j4+j5)+(j6+j7)), halves added last (rA+rB).
__device__ float x2_exact(const float* __restrict__ xr) {
#pragma clang fp contract(off)
    float rr[16];
#pragma unroll
    for (int j = 0; j < 8; ++j) {
        float a = xr[j] * xr[j];
#pragma unroll
        for (int m = 1; m < 16; ++m) { float t = xr[8 * m + j]; float s = t * t; a += s; }
        rr[j] = a;
        float b = xr[128 + j] * xr[128 + j];
#pragma unroll
        for (int m = 1; m < 16; ++m) { float t = xr[128 + 8 * m + j]; float s = t * t; b += s; }
        rr[8 + j] = b;
    }
    float a01 = rr[0] + rr[1], a23 = rr[2] + rr[3];
    float a45 = rr[4] + rr[5], a67 = rr[6] + rr[7];
    float A = (a01 + a23) + (a45 + a67);
    float b01 = rr[8] + rr[9], b23 = rr[10] + rr[11];
    float b45 = rr[12] + rr[13], b67 = rr[14] + rr[15];
    float Bt = (b01 + b23) + (b45 + b67);
    return A + Bt;
}

// ---------------------------------------------------------------------------
// Fused screen + decide + gather, BARRIER-FREE main loop.
// R5 post-mortem: the barrier-synced global_load_lds chunk structure had a
// fixed ~10 us per-chunk cost regardless of per-chunk work (R1-R5 all ~8-12
// us/chunk at 6x different work) -> staging deleted. Eh (512 KB) is
// L2-resident; each wave loads its code-quarter's MFMA A-fragments DIRECTLY
// from L2 with per-lane addresses (bit-identical fragment content to the LDS
// path). LDS is now only 6.5 KB of merge scratch; no __syncthreads until the
// final top-4 merge. Per-block tile-order rotation staggers L2 line demand
// (top-4 under the lex total order is insertion-order-independent).
// 512 thr = 8 waves; wave w: row-pair p=w&1 (rows p*32..p*32+31, 2 tiles of
// 16), code quarter grp=w>>1 (codes c*64+grp*16..+15, c=0..15).
__global__ __launch_bounds__(512, 2) void vq_fused_kernel(const float* __restrict__ X,
                                                          const unsigned short* __restrict__ Eh,
                                                          const float* __restrict__ e2g,
                                                          const float* __restrict__ E,
                                                          float* __restrict__ out0,
                                                          float* __restrict__ out1,
                                                          float* __restrict__ out2) {
    __shared__ float mv[192 * 4];   // 3 KB merge scratch
    __shared__ int   mi[192 * 4];   // 3 KB
    __shared__ int   sidx[64];

    const int tid  = threadIdx.x;
    const int w    = tid >> 6;
    const int l    = tid & 63;
    const int c16  = l & 15;
    const int quad = l >> 4;
    const int p    = w & 1;    // row-pair (rows p*32 .. p*32+31)
    const int grp  = w >> 1;   // code quarter
    const int row0 = blockIdx.x * 64;

    // ---- X fragments (B-operand): 2 tiles x 16 rows, hi only, K=256 ----
    s16x8 xh[2][8];
#pragma unroll
    for (int t = 0; t < 2; ++t) {
        const float* xrow = X + (size_t)(row0 + p * 32 + t * 16 + c16) * DIM + quad * 8;
#pragma unroll
        for (int ks = 0; ks < 8; ++ks) {
            float4 f0 = *(const float4*)(xrow + ks * 32);
            float4 f1 = *(const float4*)(xrow + ks * 32 + 4);
            float fs[8] = {f0.x, f0.y, f0.z, f0.w, f1.x, f1.y, f1.z, f1.w};
#pragma unroll
            for (int j = 0; j < 8; ++j) xh[t][ks][j] = (short)bf_rne(fs[j]);
        }
    }

    float tva[4], tvb[4];
    int   tia[4], tib[4];
#pragma unroll
    for (int s = 0; s < 4; ++s) {
        tva[s] = INFINITY; tvb[s] = INFINITY;
        tia[s] = 0x7fffffff; tib[s] = 0x7fffffff;
    }

    // ---- main loop: 16 code-tiles of this wave's quarter, no barriers ----
    const int rot = blockIdx.x & 15;
    for (int t0 = 0; t0 < 16; ++t0) {
        const int c = (t0 + rot) & 15;
        // A-fragments for codes [c*64+grp*16, +16): lane holds
        // A[m=c16][k=quad*8+j] of the 16x256 code sub-matrix (same bits the
        // LDS path delivered). 16 rows x 128 B contiguous per instruction.
        const unsigned short* ep =
            Eh + (size_t)(c * 64 + grp * 16 + c16) * DIM + quad * 8;
        s16x8 ch[8];
#pragma unroll
        for (int ks = 0; ks < 8; ++ks) ch[ks] = *(const s16x8*)(ep + ks * 32);
        f32x4 c0a = {0.f, 0.f, 0.f, 0.f};
        f32x4 c0b = c0a;
#pragma unroll
        for (int ks = 0; ks < 8; ++ks) {
            c0a = __builtin_amdgcn_mfma_f32_16x16x32_bf16(ch[ks], xh[0][ks], c0a, 0, 0, 0);
            c0b = __builtin_amdgcn_mfma_f32_16x16x32_bf16(ch[ks], xh[1][ks], c0b, 0, 0, 0);
        }
        f32x4 e2v = *(const f32x4*)(e2g + c * 64 + grp * 16 + quad * 4);
#pragma unroll
        for (int r = 0; r < 4; ++r) {
            const int code = c * 64 + grp * 16 + quad * 4 + r;
            ins4(fmaf(-2.0f, c0a[r], e2v[r]), code, tva, tia);
            ins4(fmaf(-2.0f, c0b[r], e2v[r]), code, tvb, tib);
        }
    }

    // merge top-4 across the 4 quads holding the same x-row (lanes l^16, l^32)
#pragma unroll
    for (int st = 16; st <= 32; st <<= 1) {
        float ov[4]; int oi[4];
#pragma unroll
        for (int s = 0; s < 4; ++s) {
            ov[s] = __shfl_xor(tva[s], st, 64);
            oi[s] = __shfl_xor(tia[s], st, 64);
        }
#pragma unroll
        for (int s = 0; s < 4; ++s) ins4(ov[s], oi[s], tva, tia);
#pragma unroll
        for (int s = 0; s < 4; ++s) {
            ov[s] = __shfl_xor(tvb[s], st, 64);
            oi[s] = __shfl_xor(tib[s], st, 64);
        }
#pragma unroll
        for (int s = 0; s < 4; ++s) ins4(ov[s], oi[s], tvb, tib);
    }

    // merge the 4 code-quarters (exact, order-independent lex top-4) via LDS
    if (grp >= 1 && quad == 0) {
        const int sa = (grp - 1) * 64 + p * 32 + c16;   // tile 0 slot
        const int sb = sa + 16;                          // tile 1 slot
#pragma unroll
        for (int s = 0; s < 4; ++s) {
            mv[sa * 4 + s] = tva[s]; mi[sa * 4 + s] = tia[s];
            mv[sb * 4 + s] = tvb[s]; mi[sb * 4 + s] = tib[s];
        }
    }
    __syncthreads();
    if (grp == 0 && quad == 0) {
#pragma unroll
        for (int g2 = 1; g2 < 4; ++g2) {
            const int sa = (g2 - 1) * 64 + p * 32 + c16;
            const int sb = sa + 16;
#pragma unroll
            for (int s = 0; s < 4; ++s) ins4(mv[sa * 4 + s], mi[sa * 4 + s], tva, tia);
#pragma unroll
            for (int s = 0; s < 4; ++s) ins4(mv[sb * 4 + s], mi[sb * 4 + s], tvb, tib);
        }
        // ---- decide both rows (verbatim R2-proven logic; x2 recomputed
        //      exactly in the rescue path only) ----
#pragma unroll
        for (int t = 0; t < 2; ++t) {
            float* tv = t ? tvb : tva;
            int*   ti = t ? tib : tia;
            const int r = row0 + p * 32 + t * 16 + c16;
            int best = ti[0];
            if (!(tv[1] > tv[0] + DELTA)) {
                const float* xr = X + (size_t)r * DIM;
                const float x2v = x2_exact(xr);
                float bq = INFINITY; int bi = 0x7fffffff;
                for (int cnd = 0; cnd < 4; ++cnd) {
                    if (tv[cnd] <= tv[0] + DELTA) {
                        const int k = ti[cnd];
                        const float* er = E + (size_t)k * DIM;
                        float dot = 0.f;
                        for (int d = 0; d < DIM; d += 4) {   // sequential fp32 chain
                            float4 xv = *(const float4*)(xr + d);
                            float4 ev = *(const float4*)(er + d);
                            dot = fmaf(xv.x, ev.x, dot);
                            dot = fmaf(xv.y, ev.y, dot);
                            dot = fmaf(xv.z, ev.z, dot);
                            dot = fmaf(xv.w, ev.w, dot);
                        }
                        float t1 = e2g[k] - 2.0f * dot;   // numpy elementwise rounding
                        float q  = t1 + x2v;
                        if (q < bq || (q == bq && k < bi)) { bq = q; bi = k; }
                    }
                }
                best = bi;
            }
            sidx[p * 32 + t * 16 + c16] = best;
            out2[r] = (float)best;
        }
    }
    __syncthreads();

    // ---- gather epilogue: 64 rows, coalesced float4 writes ----
#pragma unroll
    for (int it = 0; it < 8; ++it) {
        int f = tid + it * 512;
        int rr = f >> 6;
        int pp = f & 63;
        int ix = sidx[rr];
        float4 v = *(const float4*)(E + (size_t)ix * DIM + pp * 4);
        size_t o = (size_t)(row0 + rr) * DIM + (size_t)pp * 4;
        *(float4*)(out0 + o) = v;
        *(float4*)(out1 + o) = v;
    }
}

// ---------------------------------------------------------------------------
extern "C" void kernel_launch(void* const* d_in, const int* in_sizes, int n_in,
                              void* d_out, int out_size, void* d_ws, size_t ws_size,
                              hipStream_t stream) {
    const float* X = (const float*)d_in[0];
    const float* E = (const float*)d_in[1];

    // ws layout (all 16B-aligned): ~0.53 MB total
    float* e2 = (float*)d_ws;                              // 1024 f
    unsigned short* Eh = (unsigned short*)(e2 + KCODES);   // 262144 us

    float* out0 = (float*)d_out;
    float* out1 = out0 + (size_t)N_ROWS * DIM;
    float* out2 = out1 + (size_t)N_ROWS * DIM;

    prep_kernel<<<dim3(KCODES / 4), dim3(256), 0, stream>>>(E, e2, Eh);
    vq_fused_kernel<<<dim3(N_ROWS / 64), dim3(512), 0, stream>>>(X, Eh, e2, E,
                                                                 out0, out1, out2);
}